// Round 5
// baseline (599.363 us; speedup 1.0000x reference)
//
#include <hip/hip_runtime.h>
#include <math.h>

#define MU1   256
#define H     64
#define H2    128
#define SKIPC 256
#define NL    24
#define LF    80
#define UPK   4
#define REP   75
#define BB    2
#define LLEN  64
#define LL    19200

using bf16x8 = __attribute__((ext_vector_type(8))) short;
using bf16x4 = __attribute__((ext_vector_type(4))) short;
using f32x4  = __attribute__((ext_vector_type(4))) float;

__device__ __forceinline__ float b2f(short s) {
    union { unsigned u; float f; } v; v.u = ((unsigned)(unsigned short)s) << 16; return v.f;
}
__device__ __forceinline__ short f2b(float f) {
    union { float f; unsigned u; } v; v.f = f;
    unsigned r = (v.u + 0x7fff + ((v.u >> 16) & 1)) >> 16;
    return (short)r;
}

// ---------------------------------------------------------------- prep ----
__global__ __launch_bounds__(256) void prep_kernel(
    const float* __restrict__ dil_W,  const float* __restrict__ skip_W,
    const float* __restrict__ res_W,  const float* __restrict__ embed_W,
    const float* __restrict__ embed_b,const float* __restrict__ cond_W,
    const float* __restrict__ out_W1, const float* __restrict__ out_W2,
    const float* __restrict__ skip_b,
    short* __restrict__ dil_Wb, short* __restrict__ sWt,
    short* __restrict__ res_Wb, short* __restrict__ embed_allb,
    float* __restrict__ cond_Wt, short* __restrict__ W1b,
    short* __restrict__ W2b, float* __restrict__ sbsum)
{
    int idx = blockIdx.x * 256 + threadIdx.x;
    const int n1 = NL * 2 * H2 * H;     // dil_Wb[i][k][o][c]
    const int n2 = 12 * 256 * 128;      // sWt[ck][s][kc], kc=(sublayer,c)
    const int n3 = (NL - 1) * H * H;    // res_Wb[i][o][c]
    const int n4 = MU1 * H;             // embed_allb[g][h]
    const int n5 = LF * NL * H2;        // cond_Wt[c][o]
    const int n6 = MU1 * SKIPC;
    const int n7 = MU1 * MU1;
    if (idx < n1) {
        int c = idx & 63; int o = (idx >> 6) & 127;
        int k = (idx >> 13) & 1; int i = idx >> 14;
        dil_Wb[idx] = f2b(dil_W[((i * H2 + o) * H + c) * 2 + k]);
        return;
    }
    idx -= n1;
    if (idx < n2) {
        int kc = idx & 127; int s = (idx >> 7) & 255; int ck = idx >> 15;
        sWt[idx] = f2b(skip_W[((2 * ck + (kc >> 6)) * SKIPC + s) * H + (kc & 63)]);
        return;
    }
    idx -= n2;
    if (idx < n3) { res_Wb[idx] = f2b(res_W[idx]); return; }
    idx -= n3;
    if (idx < n4) {
        int h = idx & 63; int g = idx >> 6;
        embed_allb[idx] = f2b(embed_W[h * MU1 + g] + embed_b[h]);
        return;
    }
    idx -= n4;
    if (idx < n5) {
        int o = idx % (NL * H2); int c = idx / (NL * H2);
        cond_Wt[idx] = cond_W[o * LF + c];
        return;
    }
    idx -= n5;
    if (idx < n6) { W1b[idx] = f2b(out_W1[idx]); return; }
    idx -= n6;
    if (idx < n7) { W2b[idx] = f2b(out_W2[idx]); return; }
    idx -= n7;
    if (idx < SKIPC) {
        float a = 0.f;
        for (int i = 0; i < NL; i++) a += skip_b[i * SKIPC + idx];
        sbsum[idx] = a;
        return;
    }
}

// --------------------------------------------------------------- embed ----
__global__ __launch_bounds__(256) void embed_kernel(
    const int* __restrict__ gold, const short* __restrict__ eW,
    short* __restrict__ sig)
{
    int idx = blockIdx.x * 256 + threadIdx.x;
    if (idx >= BB * LL * 8) return;
    int ch = idx & 7; int bt = idx >> 3;
    int g = gold[bt];
    *(bf16x8*)(sig + (size_t)bt * H + ch * 8) = *(const bf16x8*)(eW + g * H + ch * 8);
}

// ---------------------------------------------------------------- cond ----
__global__ __launch_bounds__(256) void cond_kernel(
    const float* __restrict__ lf, const float* __restrict__ up_W,
    const float* __restrict__ up_b, const float* __restrict__ cond_Wt,
    const float* __restrict__ cond_b, const float* __restrict__ dil_b,
    float* __restrict__ condS)
{
    __shared__ float s_up[LF];
    int j = blockIdx.x;
    int ot = blockIdx.y;
    int b = blockIdx.z;
    int frame = j >> 2, k = j & 3;
    int tid = threadIdx.x;
    if (tid < LF) {
        float a = up_b[tid];
        const float* lfr = lf + (b * LLEN + frame) * LF;
        #pragma unroll 8
        for (int c = 0; c < LF; ++c) a += lfr[c] * up_W[(c * LF + tid) * UPK + k];
        s_up[tid] = a;
    }
    __syncthreads();
    int o = ot * 256 + tid;
    float a = cond_b[o] + dil_b[o];
    #pragma unroll 8
    for (int c = 0; c < LF; ++c) a += cond_Wt[c * 3072 + o] * s_up[c];
    condS[((size_t)(b * 256 + j)) * 3072 + o] = a;
}

// ---------------------------------------------------- fused layer pair ----
template<int DA, int DB, bool LASTPAIR>
__global__ __launch_bounds__(256) void pair_mfma(
    const short* __restrict__ sig_in, short* __restrict__ sig_out,
    short* __restrict__ z12,
    const short* __restrict__ dil_Wb_all,
    const short* __restrict__ res_Wb_all,
    const float* __restrict__ res_b_all,
    const float* __restrict__ condS,
    int p, int slot)
{
    __shared__ __align__(16) short sa[144][72];   // input rows [t0-48, t0+96)
    __shared__ __align__(16) short sb[128][72];   // A output rows [t0-32, t0+96)
    __shared__ __align__(16) short sz[128][72];   // z scratch
    __shared__ float scond[2][3][128];

    const int iA = 2 * p, iB = 2 * p + 1;
    const int b = blockIdx.y;
    const int t0 = blockIdx.x * 96;
    const int tid = threadIdx.x;
    const int w = tid >> 6;
    const int lane = tid & 63;
    const int lr = lane & 15, lg = lane >> 4;
    const int c0 = (t0 >= 32) ? (t0 - 32) / 75 : 0;

    // ---- stage input + cond ----
    {
        const short* basein = sig_in + (size_t)b * LL * H;
        #pragma unroll
        for (int it = 0; it < 5; ++it) {
            int task = tid + it * 256;
            if (task < 1152) {
                int r = task >> 3, ch = task & 7;
                int t = t0 - 48 + r;
                bf16x8 v = {};
                if (t >= 0) v = *(const bf16x8*)(basein + (size_t)t * H + ch * 8);
                *(bf16x8*)&sa[r][ch * 8] = v;
            }
        }
        #pragma unroll
        for (int it = 0; it < 3; ++it) {
            int task = tid + it * 256;      // 768 = 2 sel x 3 col x 128
            int sel = task >= 384;
            int cj = (task - sel * 384) >> 7;
            int o = task & 127;
            int col = c0 + cj; col = col > 255 ? 255 : col;
            scond[sel][cj][o] = condS[((size_t)(b * 256 + col)) * 3072 + (iA + sel) * 128 + o];
        }
    }
    __syncthreads();

    // ---- A gated GEMM: M=128 (2 Mtiles/wave), N=128, K=128 ----
    {
        const short* dW = dil_Wb_all + (size_t)iA * 2 * H2 * H;
        f32x4 acc[2][8];
        #pragma unroll
        for (int m = 0; m < 2; ++m)
            #pragma unroll
            for (int n = 0; n < 8; ++n) acc[m][n] = (f32x4){0.f, 0.f, 0.f, 0.f};
        bf16x8 afA[2][4];
        #pragma unroll
        for (int m = 0; m < 2; ++m) {
            int rc = 16 + 16 * (2 * w + m) + lr;
            afA[m][0] = *(const bf16x8*)&sa[rc - DA][lg * 8];
            afA[m][1] = *(const bf16x8*)&sa[rc - DA][32 + lg * 8];
            afA[m][2] = *(const bf16x8*)&sa[rc][lg * 8];
            afA[m][3] = *(const bf16x8*)&sa[rc][32 + lg * 8];
        }
        #pragma unroll
        for (int n = 0; n < 8; ++n)
            #pragma unroll
            for (int kk = 0; kk < 4; ++kk) {
                bf16x8 bw = *(const bf16x8*)(dW + (((kk >> 1) * H2 + 16 * n + lr) * H) + (kk & 1) * 32 + lg * 8);
                acc[0][n] = __builtin_amdgcn_mfma_f32_16x16x32_bf16(afA[0][kk], bw, acc[0][n], 0, 0, 0);
                acc[1][n] = __builtin_amdgcn_mfma_f32_16x16x32_bf16(afA[1][kk], bw, acc[1][n], 0, 0, 0);
            }
        #pragma unroll
        for (int m = 0; m < 2; ++m)
            #pragma unroll
            for (int n = 0; n < 4; ++n)
                #pragma unroll
                for (int r = 0; r < 4; ++r) {
                    int relt = -32 + 16 * (2 * w + m) + 4 * lg + r;
                    int t = t0 + relt;
                    int o = 16 * n + lr;
                    short zb = 0;
                    if (t >= 0) {
                        int ci = t / 75 - c0;
                        float av = acc[m][n][r] + scond[0][ci][o];
                        float gv = acc[m][n + 4][r] + scond[0][ci][64 + o];
                        float th = 1.f - 2.f / (__expf(2.f * av) + 1.f);
                        float sg = 1.f / (1.f + __expf(-gv));
                        zb = f2b(th * sg);
                    }
                    sz[relt + 32][o] = zb;
                }
    }
    __syncthreads();

    // z_A -> z12 slot, sub 0 (rows [0,96))
    #pragma unroll
    for (int it = 0; it < 3; ++it) {
        int task = tid + it * 256;
        int r = task >> 3, ch = task & 7;
        *(bf16x8*)(z12 + ((size_t)((slot * BB + b) * LL) + t0 + r) * 128 + ch * 8)
            = *(const bf16x8*)&sz[32 + r][ch * 8];
    }

    // ---- A residual: sb = sa + z @ rW + rb ----
    {
        const short* rW = res_Wb_all + (size_t)iA * H * H;
        const float* rb_ = res_b_all + (size_t)iA * H;
        f32x4 rac[2][4];
        #pragma unroll
        for (int m = 0; m < 2; ++m)
            #pragma unroll
            for (int n = 0; n < 4; ++n) rac[m][n] = (f32x4){0.f, 0.f, 0.f, 0.f};
        bf16x8 za[2][2];
        #pragma unroll
        for (int m = 0; m < 2; ++m) {
            int row = 16 * (2 * w + m) + lr;
            za[m][0] = *(const bf16x8*)&sz[row][lg * 8];
            za[m][1] = *(const bf16x8*)&sz[row][32 + lg * 8];
        }
        #pragma unroll
        for (int n = 0; n < 4; ++n)
            #pragma unroll
            for (int kk = 0; kk < 2; ++kk) {
                bf16x8 bw = *(const bf16x8*)(rW + (16 * n + lr) * H + kk * 32 + lg * 8);
                rac[0][n] = __builtin_amdgcn_mfma_f32_16x16x32_bf16(za[0][kk], bw, rac[0][n], 0, 0, 0);
                rac[1][n] = __builtin_amdgcn_mfma_f32_16x16x32_bf16(za[1][kk], bw, rac[1][n], 0, 0, 0);
            }
        #pragma unroll
        for (int n = 0; n < 4; ++n) {
            float rbv = rb_[16 * n + lr];
            #pragma unroll
            for (int m = 0; m < 2; ++m)
                #pragma unroll
                for (int r = 0; r < 4; ++r) {
                    int relt = -32 + 16 * (2 * w + m) + 4 * lg + r;
                    int t = t0 + relt;
                    int c = 16 * n + lr;
                    short vb = 0;
                    if (t >= 0) vb = f2b(b2f(sa[relt + 48][c]) + rac[m][n][r] + rbv);
                    sb[relt + 32][c] = vb;
                }
        }
    }
    __syncthreads();

    // ---- B gated GEMM: M=96 (6 Mtiles), wave w -> out channels (w, w+4) ----
    {
        const short* dW = dil_Wb_all + (size_t)iB * 2 * H2 * H;
        f32x4 accF[6], accG[6];
        #pragma unroll
        for (int m = 0; m < 6; ++m) { accF[m] = (f32x4){0.f,0.f,0.f,0.f}; accG[m] = (f32x4){0.f,0.f,0.f,0.f}; }
        bf16x8 bwF[4], bwG[4];
        #pragma unroll
        for (int kk = 0; kk < 4; ++kk) {
            int oF = 16 * w + lr;
            bwF[kk] = *(const bf16x8*)(dW + (((kk >> 1) * H2 + oF) * H) + (kk & 1) * 32 + lg * 8);
            bwG[kk] = *(const bf16x8*)(dW + (((kk >> 1) * H2 + 64 + oF) * H) + (kk & 1) * 32 + lg * 8);
        }
        #pragma unroll
        for (int m = 0; m < 6; ++m) {
            int rc = 32 + 16 * m + lr;
            bf16x8 af[4];
            af[0] = *(const bf16x8*)&sb[rc - DB][lg * 8];
            af[1] = *(const bf16x8*)&sb[rc - DB][32 + lg * 8];
            af[2] = *(const bf16x8*)&sb[rc][lg * 8];
            af[3] = *(const bf16x8*)&sb[rc][32 + lg * 8];
            #pragma unroll
            for (int kk = 0; kk < 4; ++kk)
                accF[m] = __builtin_amdgcn_mfma_f32_16x16x32_bf16(af[kk], bwF[kk], accF[m], 0, 0, 0);
            #pragma unroll
            for (int kk = 0; kk < 4; ++kk)
                accG[m] = __builtin_amdgcn_mfma_f32_16x16x32_bf16(af[kk], bwG[kk], accG[m], 0, 0, 0);
        }
        #pragma unroll
        for (int m = 0; m < 6; ++m)
            #pragma unroll
            for (int r = 0; r < 4; ++r) {
                int relt = 16 * m + 4 * lg + r;
                int t = t0 + relt;
                int o = 16 * w + lr;
                int ci = t / 75 - c0;
                float av = accF[m][r] + scond[1][ci][o];
                float gv = accG[m][r] + scond[1][ci][64 + o];
                float th = 1.f - 2.f / (__expf(2.f * av) + 1.f);
                float sg = 1.f / (1.f + __expf(-gv));
                sz[relt][o] = f2b(th * sg);
            }
    }
    __syncthreads();

    // z_B -> z12 slot, sub 1 (rows [0,96))
    #pragma unroll
    for (int it = 0; it < 3; ++it) {
        int task = tid + it * 256;
        int r = task >> 3, ch = task & 7;
        *(bf16x8*)(z12 + ((size_t)((slot * BB + b) * LL) + t0 + r) * 128 + 64 + ch * 8)
            = *(const bf16x8*)&sz[r][ch * 8];
    }

    // ---- B residual -> sig_out (rows [0,96)), wave w -> Ntile w ----
    if (!LASTPAIR) {
        const short* rW = res_Wb_all + (size_t)iB * H * H;
        const float* rb_ = res_b_all + (size_t)iB * H;
        int c = 16 * w + lr;
        f32x4 rac[6];
        #pragma unroll
        for (int m = 0; m < 6; ++m) rac[m] = (f32x4){0.f, 0.f, 0.f, 0.f};
        bf16x8 bwR[2];
        bwR[0] = *(const bf16x8*)(rW + c * H + lg * 8);
        bwR[1] = *(const bf16x8*)(rW + c * H + 32 + lg * 8);
        #pragma unroll
        for (int m = 0; m < 6; ++m) {
            bf16x8 z0 = *(const bf16x8*)&sz[16 * m + lr][lg * 8];
            bf16x8 z1 = *(const bf16x8*)&sz[16 * m + lr][32 + lg * 8];
            rac[m] = __builtin_amdgcn_mfma_f32_16x16x32_bf16(z0, bwR[0], rac[m], 0, 0, 0);
            rac[m] = __builtin_amdgcn_mfma_f32_16x16x32_bf16(z1, bwR[1], rac[m], 0, 0, 0);
        }
        float rbv = rb_[c];
        #pragma unroll
        for (int m = 0; m < 6; ++m)
            #pragma unroll
            for (int r = 0; r < 4; ++r) {
                int relt = 16 * m + 4 * lg + r;
                sa[relt][c] = f2b(b2f(sb[relt + 32][c]) + rac[m][r] + rbv);
            }
        __syncthreads();
        #pragma unroll
        for (int it = 0; it < 3; ++it) {
            int task = tid + it * 256;
            int r = task >> 3, ch = task & 7;
            *(bf16x8*)(sig_out + ((size_t)(b * LL + t0 + r)) * H + ch * 8)
                = *(const bf16x8*)&sa[r][ch * 8];
        }
    }
}

// ------------------------- wave-owned skip GEMM, layers 0-11 (K=768) ----
// 1 wave/block, 32 rows/wave, no barriers; A direct from global, B from L2.
__global__ __launch_bounds__(64, 2) void skipk_wave(
    const short* __restrict__ z12, const short* __restrict__ sWt,
    short* __restrict__ skipP)
{
    __shared__ __align__(16) short s_x[32][264];
    const int b = blockIdx.y;
    const int t0 = blockIdx.x * 32;
    const int lane = threadIdx.x;
    const int lr = lane & 15, lg = lane >> 4;

    f32x4 acc[2][16];
    #pragma unroll
    for (int mt = 0; mt < 2; ++mt)
        #pragma unroll
        for (int nt = 0; nt < 16; ++nt) acc[mt][nt] = (f32x4){0.f, 0.f, 0.f, 0.f};

    for (int ck = 0; ck < 6; ++ck) {
        const short* zb = z12 + ((size_t)((ck * BB + b) * LL) + t0) * 128;
        const short* wb = sWt + ((size_t)ck << 15);
        #pragma unroll
        for (int kk = 0; kk < 4; ++kk) {
            bf16x8 af0 = *(const bf16x8*)(zb + lr * 128 + 32 * kk + 8 * lg);
            bf16x8 af1 = *(const bf16x8*)(zb + (16 + lr) * 128 + 32 * kk + 8 * lg);
            #pragma unroll
            for (int nt = 0; nt < 16; ++nt) {
                bf16x8 bw = *(const bf16x8*)(wb + ((16 * nt + lr) << 7) + 32 * kk + 8 * lg);
                acc[0][nt] = __builtin_amdgcn_mfma_f32_16x16x32_bf16(af0, bw, acc[0][nt], 0, 0, 0);
                acc[1][nt] = __builtin_amdgcn_mfma_f32_16x16x32_bf16(af1, bw, acc[1][nt], 0, 0, 0);
            }
        }
    }
    // transpose via per-wave LDS (single wave: in-order, no barrier)
    #pragma unroll
    for (int mt = 0; mt < 2; ++mt)
        #pragma unroll
        for (int nt = 0; nt < 16; ++nt)
            #pragma unroll
            for (int reg = 0; reg < 4; ++reg)
                s_x[16 * mt + 4 * lg + reg][16 * nt + lr] = f2b(acc[mt][nt][reg]);
    #pragma unroll
    for (int i = 0; i < 16; ++i) {
        int idx = i * 64 + lane;
        int r = idx >> 5, c8 = idx & 31;
        *(bf16x8*)(skipP + ((size_t)(b * LL) + t0 + r) * 256 + c8 * 8)
            = *(const bf16x8*)&s_x[r][c8 * 8];
    }
}

// ---------- wave-owned skip (layers 12-23) + fold + head + softmax ----
__global__ __launch_bounds__(64, 2) void skiphead_wave(
    const short* __restrict__ z12, const short* __restrict__ sWt,
    const short* __restrict__ skipP, const float* __restrict__ sbsum,
    const short* __restrict__ W1b, const short* __restrict__ W2b,
    float* __restrict__ out)
{
    __shared__ __align__(16) unsigned char smem[16896];
    short (*s_x)[264] = (short(*)[264])smem;   // 32x264 bf16
    float (*s_f)[33]  = (float(*)[33])smem;    // 128x33 f32

    const int b = blockIdx.y;
    const int t0 = blockIdx.x * 32;
    const int lane = threadIdx.x;
    const int lr = lane & 15, lg = lane >> 4;

    float sb[16];
    #pragma unroll
    for (int nt = 0; nt < 16; ++nt) sb[nt] = sbsum[16 * nt + lr];

    // ---- skip GEMM K=768 (layers 12-23; slots 0-5 hold them now) ----
    f32x4 acc[2][16];
    #pragma unroll
    for (int mt = 0; mt < 2; ++mt)
        #pragma unroll
        for (int nt = 0; nt < 16; ++nt) acc[mt][nt] = (f32x4){0.f, 0.f, 0.f, 0.f};

    for (int ck = 0; ck < 6; ++ck) {
        const short* zb = z12 + ((size_t)((ck * BB + b) * LL) + t0) * 128;
        const short* wb = sWt + ((size_t)(6 + ck) << 15);
        #pragma unroll
        for (int kk = 0; kk < 4; ++kk) {
            bf16x8 af0 = *(const bf16x8*)(zb + lr * 128 + 32 * kk + 8 * lg);
            bf16x8 af1 = *(const bf16x8*)(zb + (16 + lr) * 128 + 32 * kk + 8 * lg);
            #pragma unroll
            for (int nt = 0; nt < 16; ++nt) {
                bf16x8 bw = *(const bf16x8*)(wb + ((16 * nt + lr) << 7) + 32 * kk + 8 * lg);
                acc[0][nt] = __builtin_amdgcn_mfma_f32_16x16x32_bf16(af0, bw, acc[0][nt], 0, 0, 0);
                acc[1][nt] = __builtin_amdgcn_mfma_f32_16x16x32_bf16(af1, bw, acc[1][nt], 0, 0, 0);
            }
        }
    }

    // ---- stage bf16 partial (layers 0-11), fold + relu -> x tile ----
    #pragma unroll
    for (int i = 0; i < 16; ++i) {
        int idx = i * 64 + lane;
        int r = idx >> 5, c8 = idx & 31;
        *(bf16x8*)&s_x[r][c8 * 8]
            = *(const bf16x8*)(skipP + ((size_t)(b * LL) + t0 + r) * 256 + c8 * 8);
    }
    #pragma unroll
    for (int mt = 0; mt < 2; ++mt)
        #pragma unroll
        for (int nt = 0; nt < 16; ++nt)
            #pragma unroll
            for (int reg = 0; reg < 4; ++reg) {
                int tl = 16 * mt + 4 * lg + reg, ch = 16 * nt + lr;
                float v = acc[mt][nt][reg] + b2f(s_x[tl][ch]) + sb[nt];
                s_x[tl][ch] = f2b(fmaxf(v, 0.f));
            }

    // ---- GEMM1: h = relu(x @ W1^T) ----
    f32x4 acc1[2][16];
    #pragma unroll
    for (int mt = 0; mt < 2; ++mt)
        #pragma unroll
        for (int nt = 0; nt < 16; ++nt) acc1[mt][nt] = (f32x4){0.f, 0.f, 0.f, 0.f};
    #pragma unroll
    for (int kk = 0; kk < 8; ++kk) {
        bf16x8 af0 = *(const bf16x8*)&s_x[lr][32 * kk + 8 * lg];
        bf16x8 af1 = *(const bf16x8*)&s_x[16 + lr][32 * kk + 8 * lg];
        #pragma unroll
        for (int nt = 0; nt < 16; ++nt) {
            bf16x8 bw = *(const bf16x8*)(W1b + ((size_t)(16 * nt + lr)) * MU1 + 32 * kk + 8 * lg);
            acc1[0][nt] = __builtin_amdgcn_mfma_f32_16x16x32_bf16(af0, bw, acc1[0][nt], 0, 0, 0);
            acc1[1][nt] = __builtin_amdgcn_mfma_f32_16x16x32_bf16(af1, bw, acc1[1][nt], 0, 0, 0);
        }
    }
    #pragma unroll
    for (int mt = 0; mt < 2; ++mt)
        #pragma unroll
        for (int nt = 0; nt < 16; ++nt)
            #pragma unroll
            for (int reg = 0; reg < 4; ++reg)
                s_x[16 * mt + 4 * lg + reg][16 * nt + lr] = f2b(fmaxf(acc1[mt][nt][reg], 0.f));

    // ---- GEMM2: logits ----
    f32x4 acc2[2][16];
    #pragma unroll
    for (int mt = 0; mt < 2; ++mt)
        #pragma unroll
        for (int nt = 0; nt < 16; ++nt) acc2[mt][nt] = (f32x4){0.f, 0.f, 0.f, 0.f};
    #pragma unroll
    for (int kk = 0; kk < 8; ++kk) {
        bf16x8 af0 = *(const bf16x8*)&s_x[lr][32 * kk + 8 * lg];
        bf16x8 af1 = *(const bf16x8*)&s_x[16 + lr][32 * kk + 8 * lg];
        #pragma unroll
        for (int nt = 0; nt < 16; ++nt) {
            bf16x8 bw = *(const bf16x8*)(W2b + ((size_t)(16 * nt + lr)) * MU1 + 32 * kk + 8 * lg);
            acc2[0][nt] = __builtin_amdgcn_mfma_f32_16x16x32_bf16(af0, bw, acc2[0][nt], 0, 0, 0);
            acc2[1][nt] = __builtin_amdgcn_mfma_f32_16x16x32_bf16(af1, bw, acc2[1][nt], 0, 0, 0);
        }
    }

    // ---- log-softmax over 256 channels (nt in-lane + 16-lane lr shuffle) ----
    float lse[2][4];
    #pragma unroll
    for (int mt = 0; mt < 2; ++mt)
        #pragma unroll
        for (int reg = 0; reg < 4; ++reg) {
            float m = -3.4e38f;
            #pragma unroll
            for (int nt = 0; nt < 16; ++nt) m = fmaxf(m, acc2[mt][nt][reg]);
            #pragma unroll
            for (int off = 1; off <= 8; off <<= 1) m = fmaxf(m, __shfl_xor(m, off));
            float s = 0.f;
            #pragma unroll
            for (int nt = 0; nt < 16; ++nt) s += __expf(acc2[mt][nt][reg] - m);
            #pragma unroll
            for (int off = 1; off <= 8; off <<= 1) s += __shfl_xor(s, off);
            lse[mt][reg] = m + __logf(s);
        }

    // ---- transposed store (two 128-channel passes through LDS) ----
    #pragma unroll
    for (int pass = 0; pass < 2; ++pass) {
        #pragma unroll
        for (int mt = 0; mt < 2; ++mt)
            #pragma unroll
            for (int nt8 = 0; nt8 < 8; ++nt8)
                #pragma unroll
                for (int reg = 0; reg < 4; ++reg)
                    s_f[16 * nt8 + lr][16 * mt + 4 * lg + reg]
                        = acc2[mt][8 * pass + nt8][reg] - lse[mt][reg];
        #pragma unroll
        for (int i = 0; i < 16; ++i) {
            int idx = i * 64 + lane;
            int r = idx >> 3, c4 = idx & 7;
            f32x4 v;
            v[0] = s_f[r][c4 * 4 + 0];
            v[1] = s_f[r][c4 * 4 + 1];
            v[2] = s_f[r][c4 * 4 + 2];
            v[3] = s_f[r][c4 * 4 + 3];
            *(f32x4*)(out + ((size_t)(b * MU1 + 128 * pass + r)) * LL + t0 + c4 * 4) = v;
        }
    }
}

// -------------------------------------------------------------- launch ----
extern "C" void kernel_launch(void* const* d_in, const int* in_sizes, int n_in,
                              void* d_out, int out_size, void* d_ws, size_t ws_size,
                              hipStream_t stream)
{
    const float* lf      = (const float*)d_in[0];
    const int*   gold    = (const int*)  d_in[1];
    const float* embed_W = (const float*)d_in[2];
    const float* embed_b = (const float*)d_in[3];
    const float* up_W    = (const float*)d_in[4];
    const float* up_b    = (const float*)d_in[5];
    const float* cond_W  = (const float*)d_in[6];
    const float* cond_b  = (const float*)d_in[7];
    const float* dil_W   = (const float*)d_in[8];
    const float* dil_b   = (const float*)d_in[9];
    const float* skip_W  = (const float*)d_in[10];
    const float* skip_b  = (const float*)d_in[11];
    const float* res_W   = (const float*)d_in[12];
    const float* res_b   = (const float*)d_in[13];
    const float* W1      = (const float*)d_in[14];
    const float* W2      = (const float*)d_in[15];
    float* out = (float*)d_out;

    unsigned char* p = (unsigned char*)d_ws;
    short* sigA      = (short*)p; p += (size_t)BB * LL * H * 2;          // 4.9 MB
    short* sigB      = (short*)p; p += (size_t)BB * LL * H * 2;          // 4.9 MB
    short* z12       = (short*)p; p += (size_t)6 * BB * LL * 128 * 2;    // 59 MB
    short* skipP     = (short*)p; p += (size_t)BB * LL * SKIPC * 2;      // 19.7 MB
    float* condS     = (float*)p; p += (size_t)BB * 256 * NL * H2 * 4;   // 6.3 MB
    short* dil_Wb    = (short*)p; p += (size_t)NL * 2 * H2 * H * 2;
    short* sWt       = (short*)p; p += (size_t)12 * 256 * 128 * 2;
    short* res_Wb    = (short*)p; p += (size_t)(NL - 1) * H * H * 2;
    short* embed_allb= (short*)p; p += (size_t)MU1 * H * 2;
    float* cond_Wt   = (float*)p; p += (size_t)LF * NL * H2 * 4;
    short* W1b       = (short*)p; p += (size_t)MU1 * SKIPC * 2;
    short* W2b       = (short*)p; p += (size_t)MU1 * MU1 * 2;
    float* sbsum     = (float*)p; p += (size_t)SKIPC * 4;

    const int prep_n = NL*2*H2*H + 12*256*128 + (NL-1)*H*H + MU1*H + LF*NL*H2 + MU1*SKIPC + MU1*MU1 + SKIPC;
    prep_kernel<<<(prep_n + 255) / 256, 256, 0, stream>>>(
        dil_W, skip_W, res_W, embed_W, embed_b, cond_W, W1, W2, skip_b,
        dil_Wb, sWt, res_Wb, embed_allb, cond_Wt, W1b, W2b, sbsum);

    embed_kernel<<<(BB * LL * 8 + 255) / 256, 256, 0, stream>>>(gold, embed_allb, sigA);

    cond_kernel<<<dim3(256, 12, BB), 256, 0, stream>>>(lf, up_W, up_b, cond_Wt, cond_b, dil_b, condS);

    short* si = sigA;
    short* so = sigB;
    dim3 pgrid(LL / 96, BB);   // 200 x 2
    dim3 wgrid(LL / 32, BB);   // 600 x 2 (1-wave blocks)
    for (int pp = 0; pp < 12; ++pp) {
        int slot = pp % 6;
        int r3 = pp % 3;
        if (r3 == 0)
            pair_mfma<1, 2, false><<<pgrid, 256, 0, stream>>>(si, so, z12, dil_Wb, res_Wb, res_b, condS, pp, slot);
        else if (r3 == 1)
            pair_mfma<4, 8, false><<<pgrid, 256, 0, stream>>>(si, so, z12, dil_Wb, res_Wb, res_b, condS, pp, slot);
        else if (pp == 11)
            pair_mfma<16, 32, true><<<pgrid, 256, 0, stream>>>(si, so, z12, dil_Wb, res_Wb, res_b, condS, pp, slot);
        else
            pair_mfma<16, 32, false><<<pgrid, 256, 0, stream>>>(si, so, z12, dil_Wb, res_Wb, res_b, condS, pp, slot);
        short* tmp = si; si = so; so = tmp;

        if (pp == 5)
            skipk_wave<<<wgrid, 64, 0, stream>>>(z12, sWt, skipP);
    }

    skiphead_wave<<<wgrid, 64, 0, stream>>>(z12, sWt, skipP, sbsum, W1b, W2b, out);
}